// Round 4
// baseline (3252.649 us; speedup 1.0000x reference)
//
#include <hip/hip_runtime.h>

#define DIM 1024
#define HEADS 16
#define KVHEADS 4
#define HD 64
#define SEQ 264
#define NSEQ 32            // B*T
#define NROWS (NSEQ*SEQ)   // 8448
#define NZTOK 256
#define FFN_DIM 4096

typedef __attribute__((ext_vector_type(8))) short bf16x8;
typedef __attribute__((ext_vector_type(4))) float fp32x4;

__device__ __forceinline__ unsigned short f2bf(float f) {
    unsigned int u = __builtin_bit_cast(unsigned int, f);
    u = (u + 0x7fffu + ((u >> 16) & 1u)) >> 16;
    return (unsigned short)u;
}
__device__ __forceinline__ float bf2f(unsigned short h) {
    unsigned int u = ((unsigned int)h) << 16;
    return __builtin_bit_cast(float, u);
}
__device__ __forceinline__ float4 bf4_to_f4(ushort4 u) {
    return make_float4(bf2f(u.x), bf2f(u.y), bf2f(u.z), bf2f(u.w));
}

// ---------------- fp32 -> bf16 convert (weights) ----------------
__global__ __launch_bounds__(256) void cvt_bf16(const float* __restrict__ in,
                                                unsigned short* __restrict__ out, int n4) {
    int i = blockIdx.x * 256 + threadIdx.x;
    if (i >= n4) return;
    float4 v = ((const float4*)in)[i];
    ushort4 o;
    o.x = f2bf(v.x); o.y = f2bf(v.y); o.z = f2bf(v.z); o.w = f2bf(v.w);
    ((ushort4*)out)[i] = o;
}

// ---------------- RoPE tables (NZ=256 tokens, HD=64) ----------------
__global__ void rope_tables(float* __restrict__ ct, float* __restrict__ st) {
    int z = blockIdx.x;      // token 0..255
    int d = threadIdx.x;     // dim 0..63
    int i = d & 15;          // freq index within quarter
    int p = ((d >> 4) & 1) ? (z & 15) : (z >> 4);  // quarters 0,2: row; 1,3: col
    float inv = powf(10000.f, -(float)i * (1.f / 16.f));
    float ang = (float)p * inv;
    ct[z * 64 + d] = cosf(ang);
    st[z * 64 + d] = sinf(ang);
}

// ---------------- RMSNorm over D=1024 (fp32 in, fp32 w), write bf16 -------
__global__ __launch_bounds__(256) void rmsnorm_f(const float* __restrict__ x,
                                                 const float* __restrict__ w,
                                                 unsigned short* __restrict__ out) {
    int row = blockIdx.x, t = threadIdx.x;
    float4 v = ((const float4*)x)[row * 256 + t];
    float ss = v.x * v.x + v.y * v.y + v.z * v.z + v.w * v.w;
#pragma unroll
    for (int m = 32; m >= 1; m >>= 1) ss += __shfl_xor(ss, m, 64);
    __shared__ float redbuf[4];
    if ((t & 63) == 0) redbuf[t >> 6] = ss;
    __syncthreads();
    float tot = redbuf[0] + redbuf[1] + redbuf[2] + redbuf[3];
    float sc = rsqrtf(tot * (1.0f / 1024.f) + 1e-6f);
    float4 wv = ((const float4*)w)[t];
    ushort4 o;
    o.x = f2bf(v.x * sc * wv.x);
    o.y = f2bf(v.y * sc * wv.y);
    o.z = f2bf(v.z * sc * wv.z);
    o.w = f2bf(v.w * sc * wv.w);
    ((ushort4*)out)[row * 256 + t] = o;
}

// ---------------- GEMM: C[M,N] = A[M,K] @ B[N,K]^T (bf16 in, fp32 acc) ----
// mode 0: out bf16 = acc
// mode 1: out bf16 = silu(gate[idx]) * acc   (gate bf16; in-place over gate OK)
// mode 3: out f32  = residf[idx] + acc       (in-place over residf OK)
__global__ __launch_bounds__(256) void gemm_bt(const unsigned short* __restrict__ A, int lda,
                                               const unsigned short* __restrict__ B, int ldb,
                                               int M, int N, int K, int mode,
                                               const float* residf,
                                               const unsigned short* gate,
                                               void* out) {
    int wave = threadIdx.x >> 6, lane = threadIdx.x & 63;
    int fr = lane & 15, quad = lane >> 4;
    int m0 = blockIdx.x * 64 + wave * 16;
    int n0 = blockIdx.y * 64;
    const unsigned short* ap = A + (size_t)(m0 + fr) * lda + quad * 8;
    const unsigned short* bp = B + (size_t)(n0 + fr) * ldb + quad * 8;
    size_t bstride = (size_t)16 * ldb;
    fp32x4 acc[4] = {{0.f, 0.f, 0.f, 0.f}, {0.f, 0.f, 0.f, 0.f},
                     {0.f, 0.f, 0.f, 0.f}, {0.f, 0.f, 0.f, 0.f}};
    for (int k0 = 0; k0 < K; k0 += 32) {
        bf16x8 a = *(const bf16x8*)(ap + k0);
#pragma unroll
        for (int nn = 0; nn < 4; ++nn) {
            bf16x8 b = *(const bf16x8*)(bp + nn * bstride + k0);
            acc[nn] = __builtin_amdgcn_mfma_f32_16x16x32_bf16(a, b, acc[nn], 0, 0, 0);
        }
    }
#pragma unroll
    for (int nn = 0; nn < 4; ++nn) {
#pragma unroll
        for (int r = 0; r < 4; ++r) {
            int m = m0 + quad * 4 + r;
            int n = n0 + nn * 16 + fr;
            size_t idx = (size_t)m * N + n;
            float vv = acc[nn][r];
            if (mode == 0) {
                ((unsigned short*)out)[idx] = f2bf(vv);
            } else if (mode == 1) {
                float g = bf2f(gate[idx]);
                float sg = g / (1.f + __expf(-g));
                ((unsigned short*)out)[idx] = f2bf(sg * vv);
            } else {
                ((float*)out)[idx] = residf[idx] + vv;
            }
        }
    }
}

// ---------------- fused QK RMSNorm (over HD=64) + partial 2D RoPE --------
// item = r*20 + hh; hh<16 -> q head hh, else k head hh-16. bf16 in-place.
__global__ __launch_bounds__(256) void qknorm_rope(unsigned short* __restrict__ q,
                                                   unsigned short* __restrict__ k,
                                                   const float* __restrict__ gq,
                                                   const float* __restrict__ gk,
                                                   const float* __restrict__ ct,
                                                   const float* __restrict__ st) {
    int item = blockIdx.x * 4 + (threadIdx.x >> 6);
    int lane = threadIdx.x & 63;
    int r = item / 20, hh = item % 20;
    unsigned short* base;
    const float* g;
    if (hh < 16) {
        base = q + (size_t)r * 1024 + hh * 64;
        g = gq;
    } else {
        base = k + (size_t)r * 256 + (hh - 16) * 64;
        g = gk;
    }
    float v = bf2f(base[lane]);
    float ss = v * v;
#pragma unroll
    for (int m = 32; m >= 1; m >>= 1) ss += __shfl_xor(ss, m, 64);
    float nv = v * rsqrtf(ss * (1.f / 64.f) + 1e-6f) * g[lane];
    int s = r % SEQ;
    if (s < NZTOK) {
        float partner = __shfl_xor(nv, 32, 64);
        float rot = (lane < 32) ? -partner : partner;
        nv = nv * ct[s * 64 + lane] + rot * st[s * 64 + lane];
    }
    base[lane] = f2bf(nv);
}

// ---------------- attention: block per (seq n, head h), thread per query row
__global__ __launch_bounds__(320) void attention(const unsigned short* __restrict__ q,
                                                 const unsigned short* __restrict__ k,
                                                 const unsigned short* __restrict__ v,
                                                 unsigned short* __restrict__ o) {
    __shared__ float4 ks4[64 * 16];
    __shared__ float4 vs4[64 * 16];
    int n = blockIdx.x >> 4, h = blockIdx.x & 15, kv = h >> 2;
    int tid = threadIdx.x;
    bool active = tid < SEQ;
    int s = tid;
    float4 qr[16], oa[16];
    if (active) {
        const ushort4* qp = (const ushort4*)(q + (size_t)(n * SEQ + s) * 1024 + h * 64);
#pragma unroll
        for (int i = 0; i < 16; ++i) {
            qr[i] = bf4_to_f4(qp[i]);
            oa[i] = make_float4(0.f, 0.f, 0.f, 0.f);
        }
    }
    float mx = -1e30f, l = 0.f;
    for (int c0 = 0; c0 < SEQ; c0 += 64) {
        int cnt = min(64, SEQ - c0);
        __syncthreads();
        for (int i = tid; i < cnt * 16; i += 320) {
            int j = i >> 4, d4 = i & 15;
            ks4[i] = bf4_to_f4(((const ushort4*)(k + (size_t)(n * SEQ + c0 + j) * 256 + kv * 64))[d4]);
            vs4[i] = bf4_to_f4(((const ushort4*)(v + (size_t)(n * SEQ + c0 + j) * 256 + kv * 64))[d4]);
        }
        __syncthreads();
        if (active) {
            for (int j = 0; j < cnt; ++j) {
                float sc = 0.f;
#pragma unroll
                for (int d4 = 0; d4 < 16; ++d4) {
                    float4 kk = ks4[j * 16 + d4];
                    sc += qr[d4].x * kk.x + qr[d4].y * kk.y + qr[d4].z * kk.z + qr[d4].w * kk.w;
                }
                sc *= 0.125f;  // HD^-0.5
                float t2 = __expf(sc * 0.04f);       // 50*tanh(sc/50)
                sc = 50.f * (t2 - 1.f) / (t2 + 1.f);
                if (sc > mx) {
                    float corr = __expf(mx - sc);
                    l *= corr;
#pragma unroll
                    for (int d4 = 0; d4 < 16; ++d4) {
                        oa[d4].x *= corr; oa[d4].y *= corr;
                        oa[d4].z *= corr; oa[d4].w *= corr;
                    }
                    mx = sc;
                }
                float pw = __expf(sc - mx);
                l += pw;
#pragma unroll
                for (int d4 = 0; d4 < 16; ++d4) {
                    float4 vv = vs4[j * 16 + d4];
                    oa[d4].x += pw * vv.x; oa[d4].y += pw * vv.y;
                    oa[d4].z += pw * vv.z; oa[d4].w += pw * vv.w;
                }
            }
        }
    }
    if (active) {
        float inv = 1.f / l;
        unsigned short* op = o + (size_t)(n * SEQ + s) * 1024 + h * 64;
#pragma unroll
        for (int d4 = 0; d4 < 16; ++d4) {
            ushort4 ov;
            ov.x = f2bf(oa[d4].x * inv);
            ov.y = f2bf(oa[d4].y * inv);
            ov.z = f2bf(oa[d4].z * inv);
            ov.w = f2bf(oa[d4].w * inv);
            ((ushort4*)op)[d4] = ov;
        }
    }
}

extern "C" void kernel_launch(void* const* d_in, const int* in_sizes, int n_in,
                              void* d_out, int out_size, void* d_ws, size_t ws_size,
                              hipStream_t stream) {
    const float* x   = (const float*)d_in[0];
    const float* n1w = (const float*)d_in[1];
    const float* Wq  = (const float*)d_in[2];
    const float* Wk  = (const float*)d_in[3];
    const float* Wv  = (const float*)d_in[4];
    const float* Wo  = (const float*)d_in[5];
    const float* gq  = (const float*)d_in[6];
    const float* gk  = (const float*)d_in[7];
    const float* n2w = (const float*)d_in[8];
    const float* w1  = (const float*)d_in[9];
    const float* w3  = (const float*)d_in[10];
    const float* w2  = (const float*)d_in[11];
    float* out = (float*)d_out;   // fp32 output

    char* base = (char*)d_ws;
    size_t off = 0;
    auto alloc = [&](size_t bytes) {
        void* r = base + off;
        off += (bytes + 255) & ~(size_t)255;
        return r;
    };
    // ---- bf16 weights (~29 MB) ----
    unsigned short* cWq = (unsigned short*)alloc((size_t)1024 * 1024 * 2);
    unsigned short* cWk = (unsigned short*)alloc((size_t)256 * 1024 * 2);
    unsigned short* cWv = (unsigned short*)alloc((size_t)256 * 1024 * 2);
    unsigned short* cWo = (unsigned short*)alloc((size_t)1024 * 1024 * 2);
    unsigned short* cw1 = (unsigned short*)alloc((size_t)4096 * 1024 * 2);
    unsigned short* cw3 = (unsigned short*)alloc((size_t)4096 * 1024 * 2);
    unsigned short* cw2 = (unsigned short*)alloc((size_t)4096 * 1024 * 2);
    // ---- pipeline buffers (~76 MB) ----
    unsigned short* xn = (unsigned short*)alloc((size_t)NROWS * 1024 * 2);   // xn -> o -> yb
    float* x1 = (float*)alloc((size_t)NROWS * 1024 * 4);                     // q(bf16) -> x1(fp32)
    unsigned short* kb = (unsigned short*)alloc((size_t)NROWS * 256 * 2);
    unsigned short* vb = (unsigned short*)alloc((size_t)NROWS * 256 * 2);
    unsigned short* Hb = (unsigned short*)alloc((size_t)NROWS * 1024 * 2);   // FFN quarter
    float* ct = (float*)alloc((size_t)256 * 64 * 4);
    float* st = (float*)alloc((size_t)256 * 64 * 4);
    unsigned short* qb = (unsigned short*)x1;   // q overlays x1 region
    unsigned short* ob = xn;
    unsigned short* yb = xn;

    // weight conversions fp32 -> bf16
    struct Job { const float* src; unsigned short* dst; int n; };
    Job jobs[7] = {
        {Wq, cWq, 1024 * 1024}, {Wk, cWk, 256 * 1024}, {Wv, cWv, 256 * 1024},
        {Wo, cWo, 1024 * 1024}, {w1, cw1, 4096 * 1024}, {w3, cw3, 4096 * 1024},
        {w2, cw2, 4096 * 1024}};
    for (int i = 0; i < 7; ++i) {
        int n4 = jobs[i].n / 4;
        cvt_bf16<<<(n4 + 255) / 256, 256, 0, stream>>>(jobs[i].src, jobs[i].dst, n4);
    }

    rope_tables<<<256, 64, 0, stream>>>(ct, st);

    // pre-norm 1 (fp32 x -> bf16 xn)
    rmsnorm_f<<<NROWS, 256, 0, stream>>>(x, n1w, xn);

    // QKV projections (bf16 out)
    gemm_bt<<<dim3(132, 16), 256, 0, stream>>>(xn, 1024, cWq, 1024, NROWS, 1024, 1024, 0,
                                               nullptr, nullptr, qb);
    gemm_bt<<<dim3(132, 4), 256, 0, stream>>>(xn, 1024, cWk, 1024, NROWS, 256, 1024, 0,
                                              nullptr, nullptr, kb);
    gemm_bt<<<dim3(132, 4), 256, 0, stream>>>(xn, 1024, cWv, 1024, NROWS, 256, 1024, 0,
                                              nullptr, nullptr, vb);

    // QK rmsnorm + rope (in place, bf16)
    qknorm_rope<<<(NROWS * 20) / 4, 256, 0, stream>>>(qb, kb, gq, gk, ct, st);

    // attention -> ob (bf16)
    attention<<<NSEQ * HEADS, 320, 0, stream>>>(qb, kb, vb, ob);

    // output projection + residual(x fp32) -> x1 (fp32)  [qb dead; x1 overlays]
    gemm_bt<<<dim3(132, 16), 256, 0, stream>>>(ob, 1024, cWo, 1024, NROWS, 1024, 1024, 3,
                                               x, nullptr, x1);

    // pre-norm 2 -> yb  [ob dead]
    rmsnorm_f<<<NROWS, 256, 0, stream>>>(x1, n2w, yb);

    // FFN in four K-quarters of 1024
    for (int qtr = 0; qtr < 4; ++qtr) {
        const unsigned short* w1q = cw1 + (size_t)qtr * 1024 * 1024;
        const unsigned short* w3q = cw3 + (size_t)qtr * 1024 * 1024;
        const unsigned short* w2q = cw2 + (size_t)qtr * 1024;  // col slice, ldb=4096
        gemm_bt<<<dim3(132, 16), 256, 0, stream>>>(yb, 1024, w1q, 1024, NROWS, 1024, 1024, 0,
                                                   nullptr, nullptr, Hb);
        gemm_bt<<<dim3(132, 16), 256, 0, stream>>>(yb, 1024, w3q, 1024, NROWS, 1024, 1024, 1,
                                                   nullptr, Hb, Hb);
        gemm_bt<<<dim3(132, 16), 256, 0, stream>>>(Hb, 1024, w2q, 4096, NROWS, 1024, 1024, 3,
                                                   x1, nullptr, (qtr < 3) ? (void*)x1 : (void*)out);
    }
}

// Round 5
// 1321.974 us; speedup vs baseline: 2.4604x; 2.4604x over previous
//
#include <hip/hip_runtime.h>

#define DIM 1024
#define HEADS 16
#define KVHEADS 4
#define HD 64
#define SEQ 264
#define NSEQ 32            // B*T
#define NROWS (NSEQ*SEQ)   // 8448
#define NZTOK 256
#define FFN_DIM 4096

typedef __attribute__((ext_vector_type(8))) short bf16x8;
typedef __attribute__((ext_vector_type(4))) float fp32x4;

__device__ __forceinline__ unsigned short f2bf(float f) {
    unsigned int u = __builtin_bit_cast(unsigned int, f);
    u = (u + 0x7fffu + ((u >> 16) & 1u)) >> 16;
    return (unsigned short)u;
}
__device__ __forceinline__ float bf2f(unsigned short h) {
    unsigned int u = ((unsigned int)h) << 16;
    return __builtin_bit_cast(float, u);
}
__device__ __forceinline__ float4 bf4_to_f4(ushort4 u) {
    return make_float4(bf2f(u.x), bf2f(u.y), bf2f(u.z), bf2f(u.w));
}

// async global->LDS, 16B per lane; lds dest = wave-uniform base + lane*16
__device__ __forceinline__ void gload_lds16(const unsigned short* g, unsigned short* l) {
    __builtin_amdgcn_global_load_lds((const __attribute__((address_space(1))) unsigned int*)g,
                                     (__attribute__((address_space(3))) unsigned int*)l, 16, 0, 0);
}

// ---------------- fp32 -> bf16 convert (weights) ----------------
__global__ __launch_bounds__(256) void cvt_bf16(const float* __restrict__ in,
                                                unsigned short* __restrict__ out, int n4) {
    int i = blockIdx.x * 256 + threadIdx.x;
    if (i >= n4) return;
    float4 v = ((const float4*)in)[i];
    ushort4 o;
    o.x = f2bf(v.x); o.y = f2bf(v.y); o.z = f2bf(v.z); o.w = f2bf(v.w);
    ((ushort4*)out)[i] = o;
}

// ---------------- RoPE tables (NZ=256 tokens, HD=64) ----------------
__global__ void rope_tables(float* __restrict__ ct, float* __restrict__ st) {
    int z = blockIdx.x;      // token 0..255
    int d = threadIdx.x;     // dim 0..63
    int i = d & 15;          // freq index within quarter
    int p = ((d >> 4) & 1) ? (z & 15) : (z >> 4);  // quarters 0,2: row; 1,3: col
    float inv = powf(10000.f, -(float)i * (1.f / 16.f));
    float ang = (float)p * inv;
    ct[z * 64 + d] = cosf(ang);
    st[z * 64 + d] = sinf(ang);
}

// ---------------- RMSNorm over D=1024 (fp32 in, fp32 w), write bf16 -------
__global__ __launch_bounds__(256) void rmsnorm_f(const float* __restrict__ x,
                                                 const float* __restrict__ w,
                                                 unsigned short* __restrict__ out) {
    int row = blockIdx.x, t = threadIdx.x;
    float4 v = ((const float4*)x)[row * 256 + t];
    float ss = v.x * v.x + v.y * v.y + v.z * v.z + v.w * v.w;
#pragma unroll
    for (int m = 32; m >= 1; m >>= 1) ss += __shfl_xor(ss, m, 64);
    __shared__ float redbuf[4];
    if ((t & 63) == 0) redbuf[t >> 6] = ss;
    __syncthreads();
    float tot = redbuf[0] + redbuf[1] + redbuf[2] + redbuf[3];
    float sc = rsqrtf(tot * (1.0f / 1024.f) + 1e-6f);
    float4 wv = ((const float4*)w)[t];
    ushort4 o;
    o.x = f2bf(v.x * sc * wv.x);
    o.y = f2bf(v.y * sc * wv.y);
    o.z = f2bf(v.z * sc * wv.z);
    o.w = f2bf(v.w * sc * wv.w);
    ((ushort4*)out)[row * 256 + t] = o;
}

// ---------------- GEMM 128x128 tile (m97 structure) ----------------------
// C[M,N] = A[M,K] @ B[N,K]^T, bf16 in, fp32 acc. 256 thr = 4 waves in 2x2;
// each wave 64x64 via 4x4 MFMA 16x16x32. LDS: row-major 128x32 tiles,
// staged by global_load_lds width=16 (lane i -> row i/4, col (i%4)*8).
// mode 0: out bf16 = acc
// mode 1: out bf16 = silu(gate[idx]) * acc   (gate may alias out)
// mode 3: out f32  = residf[idx] + acc       (residf may alias out)
__global__ __launch_bounds__(256) void gemm128(const unsigned short* __restrict__ A, int lda,
                                               const unsigned short* __restrict__ B, int ldb,
                                               int N, int K, int mode,
                                               const float* residf,
                                               const unsigned short* gate,
                                               void* out) {
    __shared__ unsigned short lA[128 * 32];
    __shared__ unsigned short lB[128 * 32];
    int tid = threadIdx.x;
    int wave = tid >> 6, lane = tid & 63;
    int fr = lane & 15, quad = lane >> 4;
    int m0 = blockIdx.x * 128, n0 = blockIdx.y * 128;
    int wm = (wave & 1) * 64, wn = (wave >> 1) * 64;
    // staging: each wave loads 32 rows of A-tile and 32 rows of B-tile
    int srow = lane >> 2;            // 0..15
    int scol = (lane & 3) * 8;       // 0,8,16,24
    const unsigned short* gA0 = A + (size_t)(m0 + wave * 32 + srow) * lda + scol;
    const unsigned short* gA1 = gA0 + (size_t)16 * lda;
    const unsigned short* gB0 = B + (size_t)(n0 + wave * 32 + srow) * ldb + scol;
    const unsigned short* gB1 = gB0 + (size_t)16 * ldb;
    unsigned short* lA0 = &lA[(wave * 32) * 32];
    unsigned short* lA1 = &lA[(wave * 32 + 16) * 32];
    unsigned short* lB0 = &lB[(wave * 32) * 32];
    unsigned short* lB1 = &lB[(wave * 32 + 16) * 32];

    fp32x4 acc[4][4] = {};
    for (int k0 = 0; k0 < K; k0 += 32) {
        gload_lds16(gA0 + k0, lA0);
        gload_lds16(gA1 + k0, lA1);
        gload_lds16(gB0 + k0, lB0);
        gload_lds16(gB1 + k0, lB1);
        __syncthreads();   // drains vmcnt before barrier
        bf16x8 a[4], b[4];
#pragma unroll
        for (int i = 0; i < 4; ++i)
            a[i] = *(const bf16x8*)&lA[(wm + i * 16 + fr) * 32 + quad * 8];
#pragma unroll
        for (int i = 0; i < 4; ++i)
            b[i] = *(const bf16x8*)&lB[(wn + i * 16 + fr) * 32 + quad * 8];
#pragma unroll
        for (int mi = 0; mi < 4; ++mi)
#pragma unroll
            for (int ni = 0; ni < 4; ++ni)
                acc[mi][ni] = __builtin_amdgcn_mfma_f32_16x16x32_bf16(a[mi], b[ni], acc[mi][ni], 0, 0, 0);
        __syncthreads();   // before next stage overwrites tiles
    }
#pragma unroll
    for (int mi = 0; mi < 4; ++mi) {
#pragma unroll
        for (int ni = 0; ni < 4; ++ni) {
#pragma unroll
            for (int r = 0; r < 4; ++r) {
                int m = m0 + wm + mi * 16 + quad * 4 + r;
                int n = n0 + wn + ni * 16 + fr;
                size_t idx = (size_t)m * N + n;
                float vv = acc[mi][ni][r];
                if (mode == 0) {
                    ((unsigned short*)out)[idx] = f2bf(vv);
                } else if (mode == 1) {
                    float g = bf2f(gate[idx]);
                    float sg = g / (1.f + __expf(-g));
                    ((unsigned short*)out)[idx] = f2bf(sg * vv);
                } else {
                    ((float*)out)[idx] = residf[idx] + vv;
                }
            }
        }
    }
}

// ---------------- fused QK RMSNorm (over HD=64) + partial 2D RoPE --------
// item = r*20 + hh; hh<16 -> q head hh, else k head hh-16. bf16 in-place.
__global__ __launch_bounds__(256) void qknorm_rope(unsigned short* __restrict__ q,
                                                   unsigned short* __restrict__ k,
                                                   const float* __restrict__ gq,
                                                   const float* __restrict__ gk,
                                                   const float* __restrict__ ct,
                                                   const float* __restrict__ st) {
    int item = blockIdx.x * 4 + (threadIdx.x >> 6);
    int lane = threadIdx.x & 63;
    int r = item / 20, hh = item % 20;
    unsigned short* base;
    const float* g;
    if (hh < 16) {
        base = q + (size_t)r * 1024 + hh * 64;
        g = gq;
    } else {
        base = k + (size_t)r * 256 + (hh - 16) * 64;
        g = gk;
    }
    float v = bf2f(base[lane]);
    float ss = v * v;
#pragma unroll
    for (int m = 32; m >= 1; m >>= 1) ss += __shfl_xor(ss, m, 64);
    float nv = v * rsqrtf(ss * (1.f / 64.f) + 1e-6f) * g[lane];
    int s = r % SEQ;
    if (s < NZTOK) {
        float partner = __shfl_xor(nv, 32, 64);
        float rot = (lane < 32) ? -partner : partner;
        nv = nv * ct[s * 64 + lane] + rot * st[s * 64 + lane];
    }
    base[lane] = f2bf(nv);
}

// ---------------- attention: block per (seq n, head h), thread per query row
__global__ __launch_bounds__(320) void attention(const unsigned short* __restrict__ q,
                                                 const unsigned short* __restrict__ k,
                                                 const unsigned short* __restrict__ v,
                                                 unsigned short* __restrict__ o) {
    __shared__ float4 ks4[64 * 16];
    __shared__ float4 vs4[64 * 16];
    int n = blockIdx.x >> 4, h = blockIdx.x & 15, kv = h >> 2;
    int tid = threadIdx.x;
    bool active = tid < SEQ;
    int s = tid;
    float4 qr[16], oa[16];
    if (active) {
        const ushort4* qp = (const ushort4*)(q + (size_t)(n * SEQ + s) * 1024 + h * 64);
#pragma unroll
        for (int i = 0; i < 16; ++i) {
            qr[i] = bf4_to_f4(qp[i]);
            oa[i] = make_float4(0.f, 0.f, 0.f, 0.f);
        }
    }
    float mx = -1e30f, l = 0.f;
    for (int c0 = 0; c0 < SEQ; c0 += 64) {
        int cnt = min(64, SEQ - c0);
        __syncthreads();
        for (int i = tid; i < cnt * 16; i += 320) {
            int j = i >> 4, d4 = i & 15;
            ks4[i] = bf4_to_f4(((const ushort4*)(k + (size_t)(n * SEQ + c0 + j) * 256 + kv * 64))[d4]);
            vs4[i] = bf4_to_f4(((const ushort4*)(v + (size_t)(n * SEQ + c0 + j) * 256 + kv * 64))[d4]);
        }
        __syncthreads();
        if (active) {
            for (int j = 0; j < cnt; ++j) {
                float sc = 0.f;
#pragma unroll
                for (int d4 = 0; d4 < 16; ++d4) {
                    float4 kk = ks4[j * 16 + d4];
                    sc += qr[d4].x * kk.x + qr[d4].y * kk.y + qr[d4].z * kk.z + qr[d4].w * kk.w;
                }
                sc *= 0.125f;  // HD^-0.5
                float t2 = __expf(sc * 0.04f);       // 50*tanh(sc/50)
                sc = 50.f * (t2 - 1.f) / (t2 + 1.f);
                if (sc > mx) {
                    float corr = __expf(mx - sc);
                    l *= corr;
#pragma unroll
                    for (int d4 = 0; d4 < 16; ++d4) {
                        oa[d4].x *= corr; oa[d4].y *= corr;
                        oa[d4].z *= corr; oa[d4].w *= corr;
                    }
                    mx = sc;
                }
                float pw = __expf(sc - mx);
                l += pw;
#pragma unroll
                for (int d4 = 0; d4 < 16; ++d4) {
                    float4 vv = vs4[j * 16 + d4];
                    oa[d4].x += pw * vv.x; oa[d4].y += pw * vv.y;
                    oa[d4].z += pw * vv.z; oa[d4].w += pw * vv.w;
                }
            }
        }
    }
    if (active) {
        float inv = 1.f / l;
        unsigned short* op = o + (size_t)(n * SEQ + s) * 1024 + h * 64;
#pragma unroll
        for (int d4 = 0; d4 < 16; ++d4) {
            ushort4 ov;
            ov.x = f2bf(oa[d4].x * inv);
            ov.y = f2bf(oa[d4].y * inv);
            ov.z = f2bf(oa[d4].z * inv);
            ov.w = f2bf(oa[d4].w * inv);
            ((ushort4*)op)[d4] = ov;
        }
    }
}

extern "C" void kernel_launch(void* const* d_in, const int* in_sizes, int n_in,
                              void* d_out, int out_size, void* d_ws, size_t ws_size,
                              hipStream_t stream) {
    const float* x   = (const float*)d_in[0];
    const float* n1w = (const float*)d_in[1];
    const float* Wq  = (const float*)d_in[2];
    const float* Wk  = (const float*)d_in[3];
    const float* Wv  = (const float*)d_in[4];
    const float* Wo  = (const float*)d_in[5];
    const float* gq  = (const float*)d_in[6];
    const float* gk  = (const float*)d_in[7];
    const float* n2w = (const float*)d_in[8];
    const float* w1  = (const float*)d_in[9];
    const float* w3  = (const float*)d_in[10];
    const float* w2  = (const float*)d_in[11];
    float* out = (float*)d_out;   // fp32 output

    char* base = (char*)d_ws;
    size_t off = 0;
    auto alloc = [&](size_t bytes) {
        void* r = base + off;
        off += (bytes + 255) & ~(size_t)255;
        return r;
    };
    // ---- bf16 weights (~29 MB) ----
    unsigned short* cWq = (unsigned short*)alloc((size_t)1024 * 1024 * 2);
    unsigned short* cWk = (unsigned short*)alloc((size_t)256 * 1024 * 2);
    unsigned short* cWv = (unsigned short*)alloc((size_t)256 * 1024 * 2);
    unsigned short* cWo = (unsigned short*)alloc((size_t)1024 * 1024 * 2);
    unsigned short* cw1 = (unsigned short*)alloc((size_t)4096 * 1024 * 2);
    unsigned short* cw3 = (unsigned short*)alloc((size_t)4096 * 1024 * 2);
    unsigned short* cw2 = (unsigned short*)alloc((size_t)4096 * 1024 * 2);
    // ---- pipeline buffers (~76 MB) ----
    unsigned short* xn = (unsigned short*)alloc((size_t)NROWS * 1024 * 2);   // xn -> o -> yb
    float* x1 = (float*)alloc((size_t)NROWS * 1024 * 4);                     // q(bf16) -> x1(fp32)
    unsigned short* kb = (unsigned short*)alloc((size_t)NROWS * 256 * 2);
    unsigned short* vb = (unsigned short*)alloc((size_t)NROWS * 256 * 2);
    unsigned short* Hb = (unsigned short*)alloc((size_t)NROWS * 1024 * 2);   // FFN quarter
    float* ct = (float*)alloc((size_t)256 * 64 * 4);
    float* st = (float*)alloc((size_t)256 * 64 * 4);
    unsigned short* qb = (unsigned short*)x1;   // q overlays x1 region
    unsigned short* ob = xn;
    unsigned short* yb = xn;

    // weight conversions fp32 -> bf16
    struct Job { const float* src; unsigned short* dst; int n; };
    Job jobs[7] = {
        {Wq, cWq, 1024 * 1024}, {Wk, cWk, 256 * 1024}, {Wv, cWv, 256 * 1024},
        {Wo, cWo, 1024 * 1024}, {w1, cw1, 4096 * 1024}, {w3, cw3, 4096 * 1024},
        {w2, cw2, 4096 * 1024}};
    for (int i = 0; i < 7; ++i) {
        int n4 = jobs[i].n / 4;
        cvt_bf16<<<(n4 + 255) / 256, 256, 0, stream>>>(jobs[i].src, jobs[i].dst, n4);
    }

    rope_tables<<<256, 64, 0, stream>>>(ct, st);

    // pre-norm 1 (fp32 x -> bf16 xn)
    rmsnorm_f<<<NROWS, 256, 0, stream>>>(x, n1w, xn);

    // QKV projections (bf16 out); M blocks = 8448/128 = 66
    gemm128<<<dim3(66, 8), 256, 0, stream>>>(xn, 1024, cWq, 1024, 1024, 1024, 0,
                                             nullptr, nullptr, qb);
    gemm128<<<dim3(66, 2), 256, 0, stream>>>(xn, 1024, cWk, 1024, 256, 1024, 0,
                                             nullptr, nullptr, kb);
    gemm128<<<dim3(66, 2), 256, 0, stream>>>(xn, 1024, cWv, 1024, 256, 1024, 0,
                                             nullptr, nullptr, vb);

    // QK rmsnorm + rope (in place, bf16)
    qknorm_rope<<<(NROWS * 20) / 4, 256, 0, stream>>>(qb, kb, gq, gk, ct, st);

    // attention -> ob (bf16)
    attention<<<NSEQ * HEADS, 320, 0, stream>>>(qb, kb, vb, ob);

    // output projection + residual(x fp32) -> x1 (fp32)  [qb dead; x1 overlays]
    gemm128<<<dim3(66, 8), 256, 0, stream>>>(ob, 1024, cWo, 1024, 1024, 1024, 3,
                                             x, nullptr, x1);

    // pre-norm 2 -> yb  [ob dead]
    rmsnorm_f<<<NROWS, 256, 0, stream>>>(x1, n2w, yb);

    // FFN in four K-quarters of 1024
    for (int qtr = 0; qtr < 4; ++qtr) {
        const unsigned short* w1q = cw1 + (size_t)qtr * 1024 * 1024;
        const unsigned short* w3q = cw3 + (size_t)qtr * 1024 * 1024;
        const unsigned short* w2q = cw2 + (size_t)qtr * 1024;  // col slice, ldb=4096
        gemm128<<<dim3(66, 8), 256, 0, stream>>>(yb, 1024, w1q, 1024, 1024, 1024, 0,
                                                 nullptr, nullptr, Hb);
        gemm128<<<dim3(66, 8), 256, 0, stream>>>(yb, 1024, w3q, 1024, 1024, 1024, 1,
                                                 nullptr, Hb, Hb);
        gemm128<<<dim3(66, 8), 256, 0, stream>>>(Hb, 1024, w2q, 4096, 1024, 1024, 3,
                                                 x1, nullptr, (qtr < 3) ? (void*)x1 : (void*)out);
    }
}

// Round 6
// 1009.742 us; speedup vs baseline: 3.2213x; 1.3092x over previous
//
#include <hip/hip_runtime.h>

#define DIM 1024
#define HEADS 16
#define KVHEADS 4
#define HD 64
#define SEQ 264
#define NSEQ 32            // B*T
#define NROWS (NSEQ*SEQ)   // 8448
#define NZTOK 256
#define FFN_DIM 4096

typedef __attribute__((ext_vector_type(8))) short bf16x8;
typedef __attribute__((ext_vector_type(4))) float fp32x4;

__device__ __forceinline__ unsigned short f2bf(float f) {
    unsigned int u = __builtin_bit_cast(unsigned int, f);
    u = (u + 0x7fffu + ((u >> 16) & 1u)) >> 16;
    return (unsigned short)u;
}
__device__ __forceinline__ float bf2f(unsigned short h) {
    unsigned int u = ((unsigned int)h) << 16;
    return __builtin_bit_cast(float, u);
}
__device__ __forceinline__ float4 bf4_to_f4(ushort4 u) {
    return make_float4(bf2f(u.x), bf2f(u.y), bf2f(u.z), bf2f(u.w));
}

// async global->LDS, 16B per lane; lds dest = wave-uniform base + lane*16
__device__ __forceinline__ void gload_lds16(const unsigned short* g, unsigned short* l) {
    __builtin_amdgcn_global_load_lds((const __attribute__((address_space(1))) unsigned int*)g,
                                     (__attribute__((address_space(3))) unsigned int*)l, 16, 0, 0);
}

// ---------------- fp32 -> bf16 convert (weights) ----------------
__global__ __launch_bounds__(256) void cvt_bf16(const float* __restrict__ in,
                                                unsigned short* __restrict__ out, int n4) {
    int i = blockIdx.x * 256 + threadIdx.x;
    if (i >= n4) return;
    float4 v = ((const float4*)in)[i];
    ushort4 o;
    o.x = f2bf(v.x); o.y = f2bf(v.y); o.z = f2bf(v.z); o.w = f2bf(v.w);
    ((ushort4*)out)[i] = o;
}

// ---------------- RoPE tables (NZ=256 tokens, HD=64) ----------------
__global__ void rope_tables(float* __restrict__ ct, float* __restrict__ st) {
    int z = blockIdx.x;      // token 0..255
    int d = threadIdx.x;     // dim 0..63
    int i = d & 15;          // freq index within quarter
    int p = ((d >> 4) & 1) ? (z & 15) : (z >> 4);  // quarters 0,2: row; 1,3: col
    float inv = powf(10000.f, -(float)i * (1.f / 16.f));
    float ang = (float)p * inv;
    ct[z * 64 + d] = cosf(ang);
    st[z * 64 + d] = sinf(ang);
}

// ---------------- RMSNorm over D=1024 (fp32 in, fp32 w), write bf16 -------
__global__ __launch_bounds__(256) void rmsnorm_f(const float* __restrict__ x,
                                                 const float* __restrict__ w,
                                                 unsigned short* __restrict__ out) {
    int row = blockIdx.x, t = threadIdx.x;
    float4 v = ((const float4*)x)[row * 256 + t];
    float ss = v.x * v.x + v.y * v.y + v.z * v.z + v.w * v.w;
#pragma unroll
    for (int m = 32; m >= 1; m >>= 1) ss += __shfl_xor(ss, m, 64);
    __shared__ float redbuf[4];
    if ((t & 63) == 0) redbuf[t >> 6] = ss;
    __syncthreads();
    float tot = redbuf[0] + redbuf[1] + redbuf[2] + redbuf[3];
    float sc = rsqrtf(tot * (1.0f / 1024.f) + 1e-6f);
    float4 wv = ((const float4*)w)[t];
    ushort4 o;
    o.x = f2bf(v.x * sc * wv.x);
    o.y = f2bf(v.y * sc * wv.y);
    o.z = f2bf(v.z * sc * wv.z);
    o.w = f2bf(v.w * sc * wv.w);
    ((ushort4*)out)[row * 256 + t] = o;
}

// ---------------- GEMM 128x128 tile (m97 structure) ----------------------
// C[M,N] = A[M,K] @ B[N,K]^T, bf16 in, fp32 acc. 256 thr = 4 waves in 2x2;
// each wave 64x64 via 4x4 MFMA 16x16x32. LDS: row-major 128x32 tiles,
// staged by global_load_lds width=16.
// mode 0: out bf16 = acc
// mode 1: out bf16 = silu(gate[idx]) * acc   (gate may alias out)
// mode 3: out f32  = residf[idx] + acc       (residf may alias out)
__global__ __launch_bounds__(256) void gemm128(const unsigned short* __restrict__ A, int lda,
                                               const unsigned short* __restrict__ B, int ldb,
                                               int N, int K, int mode,
                                               const float* residf,
                                               const unsigned short* gate,
                                               void* out) {
    __shared__ unsigned short lA[128 * 32];
    __shared__ unsigned short lB[128 * 32];
    int tid = threadIdx.x;
    int wave = tid >> 6, lane = tid & 63;
    int fr = lane & 15, quad = lane >> 4;
    int m0 = blockIdx.x * 128, n0 = blockIdx.y * 128;
    int wm = (wave & 1) * 64, wn = (wave >> 1) * 64;
    int srow = lane >> 2;            // 0..15
    int scol = (lane & 3) * 8;       // 0,8,16,24
    const unsigned short* gA0 = A + (size_t)(m0 + wave * 32 + srow) * lda + scol;
    const unsigned short* gA1 = gA0 + (size_t)16 * lda;
    const unsigned short* gB0 = B + (size_t)(n0 + wave * 32 + srow) * ldb + scol;
    const unsigned short* gB1 = gB0 + (size_t)16 * ldb;
    unsigned short* lA0 = &lA[(wave * 32) * 32];
    unsigned short* lA1 = &lA[(wave * 32 + 16) * 32];
    unsigned short* lB0 = &lB[(wave * 32) * 32];
    unsigned short* lB1 = &lB[(wave * 32 + 16) * 32];

    fp32x4 acc[4][4] = {};
    for (int k0 = 0; k0 < K; k0 += 32) {
        gload_lds16(gA0 + k0, lA0);
        gload_lds16(gA1 + k0, lA1);
        gload_lds16(gB0 + k0, lB0);
        gload_lds16(gB1 + k0, lB1);
        __syncthreads();
        bf16x8 a[4], b[4];
#pragma unroll
        for (int i = 0; i < 4; ++i)
            a[i] = *(const bf16x8*)&lA[(wm + i * 16 + fr) * 32 + quad * 8];
#pragma unroll
        for (int i = 0; i < 4; ++i)
            b[i] = *(const bf16x8*)&lB[(wn + i * 16 + fr) * 32 + quad * 8];
#pragma unroll
        for (int mi = 0; mi < 4; ++mi)
#pragma unroll
            for (int ni = 0; ni < 4; ++ni)
                acc[mi][ni] = __builtin_amdgcn_mfma_f32_16x16x32_bf16(a[mi], b[ni], acc[mi][ni], 0, 0, 0);
        __syncthreads();
    }
#pragma unroll
    for (int mi = 0; mi < 4; ++mi) {
#pragma unroll
        for (int ni = 0; ni < 4; ++ni) {
#pragma unroll
            for (int r = 0; r < 4; ++r) {
                int m = m0 + wm + mi * 16 + quad * 4 + r;
                int n = n0 + wn + ni * 16 + fr;
                size_t idx = (size_t)m * N + n;
                float vv = acc[mi][ni][r];
                if (mode == 0) {
                    ((unsigned short*)out)[idx] = f2bf(vv);
                } else if (mode == 1) {
                    float g = bf2f(gate[idx]);
                    float sg = g / (1.f + __expf(-g));
                    ((unsigned short*)out)[idx] = f2bf(sg * vv);
                } else {
                    ((float*)out)[idx] = residf[idx] + vv;
                }
            }
        }
    }
}

// ---------------- fused QK RMSNorm (over HD=64) + partial 2D RoPE --------
__global__ __launch_bounds__(256) void qknorm_rope(unsigned short* __restrict__ q,
                                                   unsigned short* __restrict__ k,
                                                   const float* __restrict__ gq,
                                                   const float* __restrict__ gk,
                                                   const float* __restrict__ ct,
                                                   const float* __restrict__ st) {
    int item = blockIdx.x * 4 + (threadIdx.x >> 6);
    int lane = threadIdx.x & 63;
    int r = item / 20, hh = item % 20;
    unsigned short* base;
    const float* g;
    if (hh < 16) {
        base = q + (size_t)r * 1024 + hh * 64;
        g = gq;
    } else {
        base = k + (size_t)r * 256 + (hh - 16) * 64;
        g = gk;
    }
    float v = bf2f(base[lane]);
    float ss = v * v;
#pragma unroll
    for (int m = 32; m >= 1; m >>= 1) ss += __shfl_xor(ss, m, 64);
    float nv = v * rsqrtf(ss * (1.f / 64.f) + 1e-6f) * g[lane];
    int s = r % SEQ;
    if (s < NZTOK) {
        float partner = __shfl_xor(nv, 32, 64);
        float rot = (lane < 32) ? -partner : partner;
        nv = nv * ct[s * 64 + lane] + rot * st[s * 64 + lane];
    }
    base[lane] = f2bf(nv);
}

// ---------------- MFMA flash attention -----------------------------------
// block = (n, h); 4 waves; wave handles q-tiles {wave, wave+4, ...} < 17.
// Scores S[16 x 288pad] in registers (18 fp32x4); full-row softmax; P
// streamed through per-wave 16x32 LDS chunks into PV MFMAs vs LDS V^T.
// Layouts (verified by gemm128): A/B frag [m|n=lane&15][k=quad*8+j],
// C/D col=lane&15, row=quad*4+reg.
__global__ __launch_bounds__(256) void attn_mfma(const unsigned short* __restrict__ q,
                                                 const unsigned short* __restrict__ k,
                                                 const unsigned short* __restrict__ v,
                                                 unsigned short* __restrict__ o) {
    __shared__ unsigned short VT[64 * 288];      // [hd][key], keys 264..287 zeroed
    __shared__ unsigned short Pc[4][16 * 32];    // per-wave P chunk
    int n = blockIdx.x >> 4, h = blockIdx.x & 15, kv = h >> 2;
    int tid = threadIdx.x, wave = tid >> 6, lane = tid & 63;
    int fr = lane & 15, quad = lane >> 4;
    const size_t row0 = (size_t)n * SEQ;

    // stage V^T (transpose) + zero pad columns
    for (int i = tid; i < SEQ * 16; i += 256) {
        int key = i >> 4, hd4 = (i & 15) * 4;
        ushort4 v4 = *(const ushort4*)(v + (row0 + key) * 256 + kv * 64 + hd4);
        VT[(hd4 + 0) * 288 + key] = v4.x;
        VT[(hd4 + 1) * 288 + key] = v4.y;
        VT[(hd4 + 2) * 288 + key] = v4.z;
        VT[(hd4 + 3) * 288 + key] = v4.w;
    }
    for (int i = tid; i < 64 * 24; i += 256) {
        VT[(i / 24) * 288 + 264 + (i % 24)] = 0;
    }
    __syncthreads();

    unsigned short* Pw = Pc[wave];
    for (int t = wave; t < 17; t += 4) {
        // Q A-frags (rows clamped; padded rows store-masked later)
        int qr = t * 16 + fr; if (qr > 263) qr = 263;
        const unsigned short* qp = q + (row0 + qr) * 1024 + h * 64;
        bf16x8 aq0 = *(const bf16x8*)(qp + quad * 8);
        bf16x8 aq1 = *(const bf16x8*)(qp + 32 + quad * 8);

        // scores: 17 real key-tiles, tile 17 preset to -1e30
        fp32x4 s[18];
#pragma unroll
        for (int kt = 0; kt < 17; ++kt) {
            int krow = kt * 16 + fr; if (krow > 263) krow = 263;
            const unsigned short* kp = k + (row0 + krow) * 256 + kv * 64;
            bf16x8 b0 = *(const bf16x8*)(kp + quad * 8);
            bf16x8 b1 = *(const bf16x8*)(kp + 32 + quad * 8);
            fp32x4 z = {0.f, 0.f, 0.f, 0.f};
            z = __builtin_amdgcn_mfma_f32_16x16x32_bf16(aq0, b0, z, 0, 0, 0);
            z = __builtin_amdgcn_mfma_f32_16x16x32_bf16(aq1, b1, z, 0, 0, 0);
            s[kt] = z;
        }
        s[17] = fp32x4{-1e30f, -1e30f, -1e30f, -1e30f};

        // softcap + mask invalid keys, then row max
        float mx[4] = {-1e30f, -1e30f, -1e30f, -1e30f};
#pragma unroll
        for (int kt = 0; kt < 17; ++kt) {
            int key = kt * 16 + fr;
            bool valid = key < SEQ;
#pragma unroll
            for (int r = 0; r < 4; ++r) {
                float xsc = s[kt][r] * 0.125f;
                float t2 = __expf(xsc * 0.04f);          // 50*tanh(x/50)
                float cap = 50.f * (t2 - 1.f) / (t2 + 1.f);
                cap = valid ? cap : -1e30f;
                s[kt][r] = cap;
                mx[r] = fmaxf(mx[r], cap);
            }
        }
#pragma unroll
        for (int m = 1; m <= 8; m <<= 1)
#pragma unroll
            for (int r = 0; r < 4; ++r) mx[r] = fmaxf(mx[r], __shfl_xor(mx[r], m, 64));

        // p = exp(s - m), row sum
        float l[4] = {0.f, 0.f, 0.f, 0.f};
#pragma unroll
        for (int kt = 0; kt < 18; ++kt) {
#pragma unroll
            for (int r = 0; r < 4; ++r) {
                float p = __expf(s[kt][r] - mx[r]);
                s[kt][r] = p;
                l[r] += p;
            }
        }
#pragma unroll
        for (int m = 1; m <= 8; m <<= 1)
#pragma unroll
            for (int r = 0; r < 4; ++r) l[r] += __shfl_xor(l[r], m, 64);

        // PV: stream P chunks (32 keys) through LDS, MFMA vs V^T
        fp32x4 oacc[4] = {};
#pragma unroll
        for (int c = 0; c < 9; ++c) {
#pragma unroll
            for (int half = 0; half < 2; ++half) {
                int kt = c * 2 + half;
#pragma unroll
                for (int r = 0; r < 4; ++r)
                    Pw[(quad * 4 + r) * 32 + half * 16 + fr] = f2bf(s[kt][r]);
            }
            bf16x8 a = *(const bf16x8*)&Pw[fr * 32 + quad * 8];
#pragma unroll
            for (int ni = 0; ni < 4; ++ni) {
                bf16x8 b = *(const bf16x8*)&VT[(ni * 16 + fr) * 288 + c * 32 + quad * 8];
                oacc[ni] = __builtin_amdgcn_mfma_f32_16x16x32_bf16(a, b, oacc[ni], 0, 0, 0);
            }
        }

        // store (rows quad*4+r of this q-tile)
#pragma unroll
        for (int r = 0; r < 4; ++r) {
            int qrow = t * 16 + quad * 4 + r;
            if (qrow < SEQ) {
                float inv = 1.f / l[r];
                unsigned short* op = o + (row0 + qrow) * 1024 + h * 64;
#pragma unroll
                for (int ni = 0; ni < 4; ++ni)
                    op[ni * 16 + fr] = f2bf(oacc[ni][r] * inv);
            }
        }
    }
}

extern "C" void kernel_launch(void* const* d_in, const int* in_sizes, int n_in,
                              void* d_out, int out_size, void* d_ws, size_t ws_size,
                              hipStream_t stream) {
    const float* x   = (const float*)d_in[0];
    const float* n1w = (const float*)d_in[1];
    const float* Wq  = (const float*)d_in[2];
    const float* Wk  = (const float*)d_in[3];
    const float* Wv  = (const float*)d_in[4];
    const float* Wo  = (const float*)d_in[5];
    const float* gq  = (const float*)d_in[6];
    const float* gk  = (const float*)d_in[7];
    const float* n2w = (const float*)d_in[8];
    const float* w1  = (const float*)d_in[9];
    const float* w3  = (const float*)d_in[10];
    const float* w2  = (const float*)d_in[11];
    float* out = (float*)d_out;   // fp32 output

    char* base = (char*)d_ws;
    size_t off = 0;
    auto alloc = [&](size_t bytes) {
        void* r = base + off;
        off += (bytes + 255) & ~(size_t)255;
        return r;
    };
    // ---- bf16 weights (~29 MB) ----
    unsigned short* cWq = (unsigned short*)alloc((size_t)1024 * 1024 * 2);
    unsigned short* cWk = (unsigned short*)alloc((size_t)256 * 1024 * 2);
    unsigned short* cWv = (unsigned short*)alloc((size_t)256 * 1024 * 2);
    unsigned short* cWo = (unsigned short*)alloc((size_t)1024 * 1024 * 2);
    unsigned short* cw1 = (unsigned short*)alloc((size_t)4096 * 1024 * 2);
    unsigned short* cw3 = (unsigned short*)alloc((size_t)4096 * 1024 * 2);
    unsigned short* cw2 = (unsigned short*)alloc((size_t)4096 * 1024 * 2);
    // ---- pipeline buffers (~76 MB) ----
    unsigned short* xn = (unsigned short*)alloc((size_t)NROWS * 1024 * 2);   // xn -> o -> yb
    float* x1 = (float*)alloc((size_t)NROWS * 1024 * 4);                     // q(bf16) -> x1(fp32)
    unsigned short* kb = (unsigned short*)alloc((size_t)NROWS * 256 * 2);
    unsigned short* vb = (unsigned short*)alloc((size_t)NROWS * 256 * 2);
    unsigned short* Hb = (unsigned short*)alloc((size_t)NROWS * 1024 * 2);   // FFN quarter
    float* ct = (float*)alloc((size_t)256 * 64 * 4);
    float* st = (float*)alloc((size_t)256 * 64 * 4);
    unsigned short* qb = (unsigned short*)x1;   // q overlays x1 region
    unsigned short* ob = xn;
    unsigned short* yb = xn;

    // weight conversions fp32 -> bf16
    struct Job { const float* src; unsigned short* dst; int n; };
    Job jobs[7] = {
        {Wq, cWq, 1024 * 1024}, {Wk, cWk, 256 * 1024}, {Wv, cWv, 256 * 1024},
        {Wo, cWo, 1024 * 1024}, {w1, cw1, 4096 * 1024}, {w3, cw3, 4096 * 1024},
        {w2, cw2, 4096 * 1024}};
    for (int i = 0; i < 7; ++i) {
        int n4 = jobs[i].n / 4;
        cvt_bf16<<<(n4 + 255) / 256, 256, 0, stream>>>(jobs[i].src, jobs[i].dst, n4);
    }

    rope_tables<<<256, 64, 0, stream>>>(ct, st);

    // pre-norm 1 (fp32 x -> bf16 xn)
    rmsnorm_f<<<NROWS, 256, 0, stream>>>(x, n1w, xn);

    // QKV projections (bf16 out); M blocks = 8448/128 = 66
    gemm128<<<dim3(66, 8), 256, 0, stream>>>(xn, 1024, cWq, 1024, 1024, 1024, 0,
                                             nullptr, nullptr, qb);
    gemm128<<<dim3(66, 2), 256, 0, stream>>>(xn, 1024, cWk, 1024, 256, 1024, 0,
                                             nullptr, nullptr, kb);
    gemm128<<<dim3(66, 2), 256, 0, stream>>>(xn, 1024, cWv, 1024, 256, 1024, 0,
                                             nullptr, nullptr, vb);

    // QK rmsnorm + rope (in place, bf16)
    qknorm_rope<<<(NROWS * 20) / 4, 256, 0, stream>>>(qb, kb, gq, gk, ct, st);

    // attention -> ob (bf16)
    attn_mfma<<<NSEQ * HEADS, 256, 0, stream>>>(qb, kb, vb, ob);

    // output projection + residual(x fp32) -> x1 (fp32)  [qb dead; x1 overlays]
    gemm128<<<dim3(66, 8), 256, 0, stream>>>(ob, 1024, cWo, 1024, 1024, 1024, 3,
                                             x, nullptr, x1);

    // pre-norm 2 -> yb  [ob dead]
    rmsnorm_f<<<NROWS, 256, 0, stream>>>(x1, n2w, yb);

    // FFN in four K-quarters of 1024
    for (int qtr = 0; qtr < 4; ++qtr) {
        const unsigned short* w1q = cw1 + (size_t)qtr * 1024 * 1024;
        const unsigned short* w3q = cw3 + (size_t)qtr * 1024 * 1024;
        const unsigned short* w2q = cw2 + (size_t)qtr * 1024;  // col slice, ldb=4096
        gemm128<<<dim3(66, 8), 256, 0, stream>>>(yb, 1024, w1q, 1024, 1024, 1024, 0,
                                                 nullptr, nullptr, Hb);
        gemm128<<<dim3(66, 8), 256, 0, stream>>>(yb, 1024, w3q, 1024, 1024, 1024, 1,
                                                 nullptr, Hb, Hb);
        gemm128<<<dim3(66, 8), 256, 0, stream>>>(Hb, 1024, w2q, 4096, 1024, 1024, 3,
                                                 x1, nullptr, (qtr < 3) ? (void*)x1 : (void*)out);
    }
}